// Round 6
// baseline (1022.079 us; speedup 1.0000x reference)
//
#include <hip/hip_runtime.h>
#include <math.h>

#define DIM 64
#define NT 4
#define NR 8
#define SRC_MASK 0x00FFFFFF
// tmeta layout: [0..3]=tcnt  [4..7]=tbase  [8..11]=tfill  [12]=padded_total

__global__ void zero_f(float* __restrict__ p, int n) {
    int i = blockIdx.x * blockDim.x + threadIdx.x;
    if (i < n) p[i] = 0.f;
}

__global__ void init_cnt(int* __restrict__ cnt, int* __restrict__ cnt2, int N) {
    int i = blockIdx.x * blockDim.x + threadIdx.x;
    if (i < N) { cnt[i] = 0; cnt2[i] = 0; }
}

// ---- order[] = -1 (incl. padding), tmeta zeroed ----
__global__ void init_order(int* __restrict__ order, int* __restrict__ tm, int cap) {
    int i = blockIdx.x * blockDim.x + threadIdx.x;
    if (i < cap) order[i] = -1;
    if (i < 16) tm[i] = 0;
}

// ---- per-wave ballot histogram of node types ----
__global__ void type_count(const int* __restrict__ ntype, int* __restrict__ tm, int N) {
    int i = blockIdx.x * blockDim.x + threadIdx.x;
    int t = (i < N) ? ntype[i] : -1;
    int lane = threadIdx.x & 63;
    #pragma unroll
    for (int tt = 0; tt < NT; tt++) {
        unsigned long long m = __ballot(t == tt);
        int c = __popcll(m);
        if (c && lane == (__ffsll((long long)m) - 1)) atomicAdd(&tm[tt], c);
    }
}

// ---- 64-aligned exclusive scan of 4 type counts ----
__global__ void type_scan(int* __restrict__ tm) {
    if (threadIdx.x == 0 && blockIdx.x == 0) {
        int b = 0;
        for (int t = 0; t < NT; t++) { tm[4 + t] = b; b += ((tm[t] + 63) >> 6) << 6; }
        tm[12] = b;
    }
}

// ---- scatter node ids into type-sorted order (ballot-aggregated) ----
__global__ void type_scatter(const int* __restrict__ ntype, int* __restrict__ tm,
                             int* __restrict__ order, int N) {
    int i = blockIdx.x * blockDim.x + threadIdx.x;
    int t = (i < N) ? ntype[i] : -1;
    int lane = threadIdx.x & 63;
    #pragma unroll
    for (int tt = 0; tt < NT; tt++) {
        unsigned long long m = __ballot(t == tt);
        int c = __popcll(m);
        if (!c) continue;
        int ldr = __ffsll((long long)m) - 1;
        int base = 0;
        if (lane == ldr) base = atomicAdd(&tm[8 + tt], c);
        base = __shfl(base, ldr, 64);
        if (t == tt) {
            int rank = __popcll(m & ((1ull << lane) - 1ull));
            order[tm[4 + tt] + base + rank] = i;
        }
    }
}

// ---- fused typed K/Q/V projection: 32-node tile, 3 weight mats in LDS ----
__global__ void proj_typed(const float* __restrict__ h, const int* __restrict__ ntype,
                           const int* __restrict__ order, const int* __restrict__ tm,
                           const float* __restrict__ Wk, const float* __restrict__ Wq,
                           const float* __restrict__ Wv,
                           float* __restrict__ k, float* __restrict__ q,
                           float* __restrict__ v, int N) {
    __shared__ float xs[32][68];
    __shared__ float wks[64][64], wqs[64][64], wvs[64][64];
    int t  = threadIdx.x;
    int n0 = blockIdx.x * 32;
    if (n0 >= tm[12]) return;
    int first = order[n0];
    if (first < 0) return;            // block fully in segment padding
    int ty = ntype[first];

    const float4* gk = (const float4*)(Wk + (size_t)ty * DIM * DIM);
    const float4* gq = (const float4*)(Wq + (size_t)ty * DIM * DIM);
    const float4* gv = (const float4*)(Wv + (size_t)ty * DIM * DIM);
    float4* lk = (float4*)&wks[0][0];
    float4* lq = (float4*)&wqs[0][0];
    float4* lv = (float4*)&wvs[0][0];
    #pragma unroll
    for (int i = 0; i < 4; i++) {
        lk[t + 256 * i] = gk[t + 256 * i];
        lq[t + 256 * i] = gq[t + 256 * i];
        lv[t + 256 * i] = gv[t + 256 * i];
    }
    #pragma unroll
    for (int i = 0; i < 2; i++) {
        int idx = t + 256 * i;               // 512 float4 slots = 32 rows x 16
        int row = idx >> 4, c4 = idx & 15;
        int gn = order[n0 + row];
        float4 xv = make_float4(0.f, 0.f, 0.f, 0.f);
        if (gn >= 0) xv = ((const float4*)(h + (size_t)gn * DIM))[c4];
        ((float4*)&xs[row][0])[c4] = xv;
    }
    __syncthreads();

    int node = t >> 3;          // 0..31
    int og   = (t & 7) * 2;     // two float4 column groups: og, og+1
    float4 ak0 = make_float4(0.f,0.f,0.f,0.f), ak1 = ak0;
    float4 aq0 = ak0, aq1 = ak0, av0 = ak0, av1 = ak0;
    #pragma unroll 8
    for (int d = 0; d < DIM; d++) {
        float xv = xs[node][d];
        float4 k0 = ((const float4*)&wks[d][0])[og], k1 = ((const float4*)&wks[d][0])[og + 1];
        float4 q0 = ((const float4*)&wqs[d][0])[og], q1 = ((const float4*)&wqs[d][0])[og + 1];
        float4 v0 = ((const float4*)&wvs[d][0])[og], v1 = ((const float4*)&wvs[d][0])[og + 1];
        ak0.x = fmaf(xv, k0.x, ak0.x); ak0.y = fmaf(xv, k0.y, ak0.y);
        ak0.z = fmaf(xv, k0.z, ak0.z); ak0.w = fmaf(xv, k0.w, ak0.w);
        ak1.x = fmaf(xv, k1.x, ak1.x); ak1.y = fmaf(xv, k1.y, ak1.y);
        ak1.z = fmaf(xv, k1.z, ak1.z); ak1.w = fmaf(xv, k1.w, ak1.w);
        aq0.x = fmaf(xv, q0.x, aq0.x); aq0.y = fmaf(xv, q0.y, aq0.y);
        aq0.z = fmaf(xv, q0.z, aq0.z); aq0.w = fmaf(xv, q0.w, aq0.w);
        aq1.x = fmaf(xv, q1.x, aq1.x); aq1.y = fmaf(xv, q1.y, aq1.y);
        aq1.z = fmaf(xv, q1.z, aq1.z); aq1.w = fmaf(xv, q1.w, aq1.w);
        av0.x = fmaf(xv, v0.x, av0.x); av0.y = fmaf(xv, v0.y, av0.y);
        av0.z = fmaf(xv, v0.z, av0.z); av0.w = fmaf(xv, v0.w, av0.w);
        av1.x = fmaf(xv, v1.x, av1.x); av1.y = fmaf(xv, v1.y, av1.y);
        av1.z = fmaf(xv, v1.z, av1.z); av1.w = fmaf(xv, v1.w, av1.w);
    }
    int gn = order[n0 + node];
    if (gn >= 0) {
        float4* kp = (float4*)(k + (size_t)gn * DIM);
        float4* qp = (float4*)(q + (size_t)gn * DIM);
        float4* vp = (float4*)(v + (size_t)gn * DIM);
        kp[og] = ak0; kp[og + 1] = ak1;
        qp[og] = aq0; qp[og + 1] = aq1;
        vp[og] = av0; vp[og + 1] = av1;
    }
}

// ---------------- CSR build: histogram of dst ----------------
__global__ void hist_kernel(const int* __restrict__ dst, int* __restrict__ cnt, int E) {
    int e = blockIdx.x * blockDim.x + threadIdx.x;
    if (e < E) atomicAdd(&cnt[dst[e]], 1);
}

// ------- 3-dispatch parallel exclusive scan: cnt[N] -> off[N+1] -------
__global__ void scan1(const int* __restrict__ cnt, int* __restrict__ off,
                      int* __restrict__ bsum, int N) {
    __shared__ int buf[1024];
    int tid = threadIdx.x;
    int i = blockIdx.x * 1024 + tid;
    int x = (i < N) ? cnt[i] : 0;
    buf[tid] = x;
    __syncthreads();
    for (int s = 1; s < 1024; s <<= 1) {
        int t = (tid >= s) ? buf[tid - s] : 0;
        __syncthreads();
        buf[tid] += t;
        __syncthreads();
    }
    if (i < N) off[i] = buf[tid] - x;
    if (tid == 1023) bsum[blockIdx.x] = buf[1023];
}

__global__ void scan2(int* __restrict__ bsum, int nb) {
    __shared__ int buf[1024];
    __shared__ int carry;
    int tid = threadIdx.x;
    if (tid == 0) carry = 0;
    __syncthreads();
    for (int base = 0; base < nb; base += 1024) {
        int i = base + tid;
        int x = (i < nb) ? bsum[i] : 0;
        buf[tid] = x;
        __syncthreads();
        for (int s = 1; s < 1024; s <<= 1) {
            int t = (tid >= s) ? buf[tid - s] : 0;
            __syncthreads();
            buf[tid] += t;
            __syncthreads();
        }
        if (i < nb) bsum[i] = carry + buf[tid] - x;
        __syncthreads();
        if (tid == 1023) carry += buf[1023];
        __syncthreads();
    }
}

__global__ void scan3(int* __restrict__ off, const int* __restrict__ bsum, int N, int E) {
    int i = blockIdx.x * 1024 + threadIdx.x;
    if (i < N) off[i] += bsum[blockIdx.x];
    if (i == 0) off[N] = E;
}

__global__ void scatter_kernel(const int* __restrict__ src, const int* __restrict__ dst,
                               const int* __restrict__ et, const int* __restrict__ off,
                               int* __restrict__ cnt2, int* __restrict__ se, int E) {
    int e = blockIdx.x * blockDim.x + threadIdx.x;
    if (e >= E) return;
    int d = dst[e];
    int p = off[d] + atomicAdd(&cnt2[d], 1);
    se[p] = (et[e] << 24) | src[e];
}

// ------- apply_rel as LDS-blocked GEMM: 64 nodes x 64 cols per block -------
__global__ void apply_rel_gemm(const float* __restrict__ x, const float* __restrict__ Wr,
                               float* __restrict__ out, int N, int r0) {
    __shared__ float xs[64][68];
    __shared__ float wsm[64][64];
    int t  = threadIdx.x;
    int r  = r0 + blockIdx.y;
    int n0 = blockIdx.x * 64;

    const float4* wg = (const float4*)(Wr + (size_t)r * DIM * DIM);
    float4* wl = (float4*)&wsm[0][0];
    #pragma unroll
    for (int i = 0; i < 4; i++) wl[t + 256 * i] = wg[t + 256 * i];
    #pragma unroll
    for (int i = 0; i < 4; i++) {
        int idx = t + 256 * i;
        int row = idx >> 4, c4 = idx & 15;
        int gn = n0 + row;
        float4 xv = make_float4(0.f, 0.f, 0.f, 0.f);
        if (gn < N) xv = ((const float4*)(x + (size_t)gn * DIM))[c4];
        ((float4*)&xs[row][0])[c4] = xv;
    }
    __syncthreads();

    int og  = t & 15;
    int ng4 = (t >> 4) * 4;
    float4 a0 = make_float4(0.f,0.f,0.f,0.f), a1 = a0, a2 = a0, a3 = a0;
    #pragma unroll 8
    for (int d = 0; d < DIM; d++) {
        float4 wv = ((const float4*)&wsm[d][0])[og];
        float x0 = xs[ng4 + 0][d];
        float x1 = xs[ng4 + 1][d];
        float x2 = xs[ng4 + 2][d];
        float x3 = xs[ng4 + 3][d];
        a0.x = fmaf(x0, wv.x, a0.x); a0.y = fmaf(x0, wv.y, a0.y);
        a0.z = fmaf(x0, wv.z, a0.z); a0.w = fmaf(x0, wv.w, a0.w);
        a1.x = fmaf(x1, wv.x, a1.x); a1.y = fmaf(x1, wv.y, a1.y);
        a1.z = fmaf(x1, wv.z, a1.z); a1.w = fmaf(x1, wv.w, a1.w);
        a2.x = fmaf(x2, wv.x, a2.x); a2.y = fmaf(x2, wv.y, a2.y);
        a2.z = fmaf(x2, wv.z, a2.z); a2.w = fmaf(x2, wv.w, a2.w);
        a3.x = fmaf(x3, wv.x, a3.x); a3.y = fmaf(x3, wv.y, a3.y);
        a3.z = fmaf(x3, wv.z, a3.z); a3.w = fmaf(x3, wv.w, a3.w);
    }
    float* ob = out + (size_t)blockIdx.y * N * DIM;
    if (n0 + ng4 + 0 < N) ((float4*)(ob + (size_t)(n0 + ng4 + 0) * DIM))[og] = a0;
    if (n0 + ng4 + 1 < N) ((float4*)(ob + (size_t)(n0 + ng4 + 1) * DIM))[og] = a1;
    if (n0 + ng4 + 2 < N) ((float4*)(ob + (size_t)(n0 + ng4 + 2) * DIM))[og] = a2;
    if (n0 + ng4 + 3 < N) ((float4*)(ob + (size_t)(n0 + ng4 + 3) * DIM))[og] = a3;
}

// ------- score over CSR (+fused den): 16-lane group per dst node -------
__global__ void score_csr(const float* __restrict__ qW, const float* __restrict__ k,
                          const int* __restrict__ se, const int* __restrict__ off,
                          const float* __restrict__ rel_pri,
                          float* __restrict__ ex, float* __restrict__ den,
                          int N, int r0, int r1) {
    int n  = blockIdx.x * 16 + (threadIdx.x >> 4);
    int ll = threadIdx.x & 15;
    if (n >= N) return;
    int i0 = off[n], i1 = off[n + 1];
    float dl = 0.f;
    for (int i = i0; i < i1; i++) {
        int sev = se[i];
        int r = sev >> 24;
        if (r < r0 || r >= r1) continue;
        int s = sev & SRC_MASK;
        float4 a = ((const float4*)(qW + ((size_t)(r - r0) * N + n) * DIM))[ll];
        float4 b = ((const float4*)(k + (size_t)s * DIM))[ll];
        float p = a.x * b.x + a.y * b.y + a.z * b.z + a.w * b.w;
        p += __shfl_xor(p, 8, 16);
        p += __shfl_xor(p, 4, 16);
        p += __shfl_xor(p, 2, 16);
        p += __shfl_xor(p, 1, 16);
        if (ll == 0) {
            float e_ = expf(p * rel_pri[r] * 0.125f);  // logits tiny: no max-shift
            ex[i] = e_;
            dl += e_;
        }
    }
    if (ll == 0) den[n] = (r0 == 0) ? dl : den[n] + dl;
}

// ------- aggregate over CSR: 16-lane group per dst node, no atomics -------
__global__ void agg_csr(const float* __restrict__ vW, const float* __restrict__ ex,
                        const int* __restrict__ se, const int* __restrict__ off,
                        const float* __restrict__ den, float* __restrict__ agg,
                        int N, int r0, int r1, int first) {
    int n  = blockIdx.x * 16 + (threadIdx.x >> 4);
    int ll = threadIdx.x & 15;
    if (n >= N) return;
    int i0 = off[n], i1 = off[n + 1];
    float dn = den[n];
    float inv = (dn == 0.f) ? 0.f : 1.f / dn;
    float4 acc = make_float4(0.f, 0.f, 0.f, 0.f);
    for (int i = i0; i < i1; i++) {
        int sev = se[i];
        int r = sev >> 24;
        if (r < r0 || r >= r1) continue;
        int s = sev & SRC_MASK;
        float alpha = ex[i] * inv;
        float4 mv = ((const float4*)(vW + ((size_t)(r - r0) * N + s) * DIM))[ll];
        acc.x = fmaf(alpha, mv.x, acc.x);
        acc.y = fmaf(alpha, mv.y, acc.y);
        acc.z = fmaf(alpha, mv.z, acc.z);
        acc.w = fmaf(alpha, mv.w, acc.w);
    }
    float4* ap = (float4*)(agg + (size_t)n * DIM) + ll;
    if (first) *ap = acc;
    else {
        float4 o = *ap;
        o.x += acc.x; o.y += acc.y; o.z += acc.z; o.w += acc.w;
        *ap = o;
    }
}

// ------- typed output GEMM: 64-node tile, sigmoid(skip)*W staged in LDS -------
__global__ void out_typed(const float* __restrict__ agg, const int* __restrict__ ntype,
                          const int* __restrict__ order, const int* __restrict__ tm,
                          const float* __restrict__ Wa, const float* __restrict__ skip,
                          float* __restrict__ out, int N) {
    __shared__ float xs[64][68];
    __shared__ float wsm[64][64];
    int t  = threadIdx.x;
    int n0 = blockIdx.x * 64;
    if (n0 >= tm[12]) return;
    int first = order[n0];
    if (first < 0) return;
    int ty = ntype[first];
    float sg = 1.f / (1.f + expf(-skip[ty]));

    const float4* wg = (const float4*)(Wa + (size_t)ty * DIM * DIM);
    float4* wl = (float4*)&wsm[0][0];
    #pragma unroll
    for (int i = 0; i < 4; i++) {
        float4 w = wg[t + 256 * i];
        w.x *= sg; w.y *= sg; w.z *= sg; w.w *= sg;
        wl[t + 256 * i] = w;
    }
    #pragma unroll
    for (int i = 0; i < 4; i++) {
        int idx = t + 256 * i;
        int row = idx >> 4, c4 = idx & 15;
        int gn = order[n0 + row];
        float4 xv = make_float4(0.f, 0.f, 0.f, 0.f);
        if (gn >= 0) xv = ((const float4*)(agg + (size_t)gn * DIM))[c4];
        ((float4*)&xs[row][0])[c4] = xv;
    }
    __syncthreads();

    int og  = t & 15;
    int ng4 = (t >> 4) * 4;
    float4 a0 = make_float4(0.f,0.f,0.f,0.f), a1 = a0, a2 = a0, a3 = a0;
    #pragma unroll 8
    for (int d = 0; d < DIM; d++) {
        float4 wv = ((const float4*)&wsm[d][0])[og];
        float x0 = xs[ng4 + 0][d];
        float x1 = xs[ng4 + 1][d];
        float x2 = xs[ng4 + 2][d];
        float x3 = xs[ng4 + 3][d];
        a0.x = fmaf(x0, wv.x, a0.x); a0.y = fmaf(x0, wv.y, a0.y);
        a0.z = fmaf(x0, wv.z, a0.z); a0.w = fmaf(x0, wv.w, a0.w);
        a1.x = fmaf(x1, wv.x, a1.x); a1.y = fmaf(x1, wv.y, a1.y);
        a1.z = fmaf(x1, wv.z, a1.z); a1.w = fmaf(x1, wv.w, a1.w);
        a2.x = fmaf(x2, wv.x, a2.x); a2.y = fmaf(x2, wv.y, a2.y);
        a2.z = fmaf(x2, wv.z, a2.z); a2.w = fmaf(x2, wv.w, a2.w);
        a3.x = fmaf(x3, wv.x, a3.x); a3.y = fmaf(x3, wv.y, a3.y);
        a3.z = fmaf(x3, wv.z, a3.z); a3.w = fmaf(x3, wv.w, a3.w);
    }
    int g0 = order[n0 + ng4 + 0];
    int g1 = order[n0 + ng4 + 1];
    int g2 = order[n0 + ng4 + 2];
    int g3 = order[n0 + ng4 + 3];
    if (g0 >= 0) ((float4*)(out + (size_t)g0 * DIM))[og] = a0;
    if (g1 >= 0) ((float4*)(out + (size_t)g1 * DIM))[og] = a1;
    if (g2 >= 0) ((float4*)(out + (size_t)g2 * DIM))[og] = a2;
    if (g3 >= 0) ((float4*)(out + (size_t)g3 * DIM))[og] = a3;
}

// ------- fallback (tiny ws): per-edge bilinear with atomics -------
__global__ void score_direct(const float* __restrict__ q, const float* __restrict__ k,
                             const int* __restrict__ src, const int* __restrict__ dst,
                             const int* __restrict__ et, const float* __restrict__ A,
                             const float* __restrict__ rel_pri,
                             float* __restrict__ ex, float* __restrict__ den, int E) {
    int e = (blockIdx.x * blockDim.x + threadIdx.x) >> 6;
    int l = threadIdx.x & 63;
    if (e >= E) return;
    int s = src[e], d = dst[e], r = et[e];
    float qv = q[(size_t)d * DIM + l];
    const float* a = A + (size_t)r * DIM * DIM;
    float t = 0.f;
    #pragma unroll 16
    for (int dd = 0; dd < DIM; dd++)
        t = fmaf(__shfl(qv, dd, 64), a[dd * DIM + l], t);
    float p = t * k[(size_t)s * DIM + l];
    #pragma unroll
    for (int off = 32; off > 0; off >>= 1) p += __shfl_xor(p, off, 64);
    if (l == 0) {
        float e_ = expf(p * rel_pri[r] * 0.125f);
        ex[e] = e_;
        atomicAdd(&den[d], e_);
    }
}

__global__ void agg_direct(const float* __restrict__ v, const float* __restrict__ ex,
                           const int* __restrict__ src, const int* __restrict__ dst,
                           const int* __restrict__ et, const float* __restrict__ Mw,
                           const float* __restrict__ den,
                           float* __restrict__ agg, int E) {
    int e = (blockIdx.x * blockDim.x + threadIdx.x) >> 6;
    int l = threadIdx.x & 63;
    if (e >= E) return;
    int s = src[e], d = dst[e], r = et[e];
    float vv = v[(size_t)s * DIM + l];
    const float* w = Mw + (size_t)r * DIM * DIM;
    float t = 0.f;
    #pragma unroll 16
    for (int dd = 0; dd < DIM; dd++)
        t = fmaf(__shfl(vv, dd, 64), w[dd * DIM + l], t);
    float dn = den[d];
    float alpha = ex[e] / (dn == 0.f ? 1.f : dn);
    atomicAdd(&agg[(size_t)d * DIM + l], alpha * t);
}

extern "C" void kernel_launch(void* const* d_in, const int* in_sizes, int n_in,
                              void* d_out, int out_size, void* d_ws, size_t ws_size,
                              hipStream_t stream) {
    const float* h       = (const float*)d_in[0];
    const int*   ntype   = (const int*)  d_in[1];
    const int*   src     = (const int*)  d_in[2];
    const int*   dst     = (const int*)  d_in[3];
    const int*   et      = (const int*)  d_in[4];
    const float* k_lin   = (const float*)d_in[5];
    const float* q_lin   = (const float*)d_in[6];
    const float* v_lin   = (const float*)d_in[7];
    const float* a_lin   = (const float*)d_in[8];
    const float* rel_att = (const float*)d_in[9];
    const float* rel_msg = (const float*)d_in[10];
    const float* rel_pri = (const float*)d_in[11];
    const float* skip    = (const float*)d_in[12];

    int N = in_sizes[1];
    int E = in_sizes[2];
    int ocap = N + NT * 64;

    float* ws = (float*)d_ws;
    size_t o = 0;
    float* k     = ws + o; o += (size_t)N * DIM;   // agg overlays k later
    float* q     = ws + o; o += (size_t)N * DIM;
    float* v     = ws + o; o += (size_t)N * DIM;
    float* ex    = ws + o; o += (size_t)E;
    float* den   = ws + o; o += (size_t)N;
    int*   off   = (int*)(ws + o); o += (size_t)N + 1;
    int*   cnt   = (int*)(ws + o); o += (size_t)N;
    int*   cnt2  = (int*)(ws + o); o += (size_t)N;
    int*   se    = (int*)(ws + o); o += (size_t)E;
    int*   bsum  = (int*)(ws + o); o += 1024;
    int*   order = (int*)(ws + o); o += (size_t)ocap;
    int*   tm    = (int*)(ws + o); o += 16;
    size_t fixed = o;
    float* agg = k;   // k dead after score phase

    size_t ws_floats = ws_size / sizeof(float);
    size_t avail = (ws_floats > fixed) ? (ws_floats - fixed) : 0;
    int C = (int)(avail / ((size_t)N * DIM));
    if (C > NR) C = NR;
    float* rbuf = ws + fixed;

    float* out = (float*)d_out;

    // ---- type sort ----
    init_order<<<(ocap + 255) / 256, 256, 0, stream>>>(order, tm, ocap);
    type_count<<<(N + 255) / 256, 256, 0, stream>>>(ntype, tm, N);
    type_scan<<<1, 64, 0, stream>>>(tm);
    type_scatter<<<(N + 255) / 256, 256, 0, stream>>>(ntype, tm, order, N);

    // ---- typed fused projections ----
    int gridP = (N + NT * 64 + 31) / 32;
    proj_typed<<<gridP, 256, 0, stream>>>(h, ntype, order, tm, k_lin, q_lin, v_lin,
                                          k, q, v, N);

    if (C >= 1) {
        // ---- CSR build ----
        init_cnt<<<(N + 255) / 256, 256, 0, stream>>>(cnt, cnt2, N);
        hist_kernel<<<(E + 255) / 256, 256, 0, stream>>>(dst, cnt, E);
        int nb = (N + 1023) / 1024;
        scan1<<<nb, 1024, 0, stream>>>(cnt, off, bsum, N);
        scan2<<<1, 1024, 0, stream>>>(bsum, nb);
        scan3<<<nb, 1024, 0, stream>>>(off, bsum, N, E);
        scatter_kernel<<<(E + 255) / 256, 256, 0, stream>>>(src, dst, et, off, cnt2, se, E);

        int nb16 = (N + 15) / 16;
        int nb64 = (N + 63) / 64;
        for (int r0 = 0; r0 < NR; r0 += C) {
            int r1 = r0 + C < NR ? r0 + C : NR;
            apply_rel_gemm<<<dim3(nb64, r1 - r0), 256, 0, stream>>>(q, rel_att, rbuf, N, r0);
            score_csr<<<nb16, 256, 0, stream>>>(rbuf, k, se, off, rel_pri, ex, den, N, r0, r1);
        }
        for (int r0 = 0; r0 < NR; r0 += C) {
            int r1 = r0 + C < NR ? r0 + C : NR;
            apply_rel_gemm<<<dim3(nb64, r1 - r0), 256, 0, stream>>>(v, rel_msg, rbuf, N, r0);
            agg_csr<<<nb16, 256, 0, stream>>>(rbuf, ex, se, off, den, agg, N, r0, r1,
                                              r0 == 0 ? 1 : 0);
        }
    } else {
        // ---- workspace-starved fallback ----
        zero_f<<<(N + 255) / 256, 256, 0, stream>>>(den, N);
        score_direct<<<(E + 3) / 4, 256, 0, stream>>>(q, k, src, dst, et, rel_att, rel_pri,
                                                      ex, den, E);
        zero_f<<<(N * DIM + 255) / 256, 256, 0, stream>>>(agg, N * DIM);
        agg_direct<<<(E + 3) / 4, 256, 0, stream>>>(v, ex, src, dst, et, rel_msg,
                                                    den, agg, E);
    }

    // ---- typed output GEMM ----
    int gridO = (N + NT * 64 + 63) / 64;
    out_typed<<<gridO, 256, 0, stream>>>(agg, ntype, order, tm, a_lin, skip, out, N);
}